// Round 6
// baseline (552.154 us; speedup 1.0000x reference)
//
#include <hip/hip_runtime.h>
#include <math.h>

#define D_MODEL 1024
#define D_STATE 32
#define D_INNER 2048
#define DT_RANK 64
#define BT 4096            // B*T = 2*2048
#define XZLD 4224          // xz_aug row stride (4096 + 128)
#define LN_EPS 1e-5f

typedef __attribute__((ext_vector_type(8))) short short8;
typedef __attribute__((ext_vector_type(4))) float f32x4;
typedef const __attribute__((address_space(1))) void* gp_t;
typedef __attribute__((address_space(3))) void* lp_t;

__device__ __forceinline__ ushort bf16r(float f) {
    unsigned u = __float_as_uint(f);
    u += 0x7fff + ((u >> 16) & 1);          // round-to-nearest-even
    return (ushort)(u >> 16);
}

// 32-lane sum via DPP (VALU pipe, no LDS). Result lands in lanes 31 and 63.
__device__ __forceinline__ float dpp_red32(float x) {
    int t;
    t = __builtin_amdgcn_update_dpp(0, __float_as_int(x), 0x111, 0xf, 0xf, true); // row_shr:1
    x += __int_as_float(t);
    t = __builtin_amdgcn_update_dpp(0, __float_as_int(x), 0x112, 0xf, 0xf, true); // row_shr:2
    x += __int_as_float(t);
    t = __builtin_amdgcn_update_dpp(0, __float_as_int(x), 0x114, 0xf, 0xf, true); // row_shr:4
    x += __int_as_float(t);
    t = __builtin_amdgcn_update_dpp(0, __float_as_int(x), 0x118, 0xf, 0xf, true); // row_shr:8
    x += __int_as_float(t);
    t = __builtin_amdgcn_update_dpp(0, __float_as_int(x), 0x142, 0xa, 0xf, true); // row_bcast:15
    x += __int_as_float(t);
    return x;
}

// ---------------------------------------------------------------- fp32 -> bf16
__global__ __launch_bounds__(256) void cvt_bf16(const float* __restrict__ in,
                                                ushort* __restrict__ out, int n4) {
    int i = blockIdx.x * 256 + threadIdx.x;
    if (i >= n4) return;
    float4 v = ((const float4*)in)[i];
    ushort4 o;
    o.x = bf16r(v.x); o.y = bf16r(v.y); o.z = bf16r(v.z); o.w = bf16r(v.w);
    ((ushort4*)out)[i] = o;
}

// ------------------------------------------- dt_low cols of xz_aug -> bf16 dense
__global__ __launch_bounds__(256) void cvt_dtlow(const float* __restrict__ xz,
                                                 ushort* __restrict__ out) {
    int i = blockIdx.x * 256 + threadIdx.x;   // 0 .. 65536
    int row = i >> 4, c = (i & 15) << 2;
    float4 v = *(const float4*)&xz[(size_t)row * XZLD + 4096 + c];
    ushort4 o;
    o.x = bf16r(v.x); o.y = bf16r(v.y); o.z = bf16r(v.z); o.w = bf16r(v.w);
    ((ushort4*)out)[i] = o;
}

// ---------------------------------------------------------------- transpose + cvt
// in: fp32 [2048,1024] -> out: bf16 [1024,2048]
__global__ __launch_bounds__(256) void transpose_cvt(const float* __restrict__ in,
                                                     ushort* __restrict__ out) {
    __shared__ float tile[32][33];
    int bx = blockIdx.x * 32;   // e base
    int by = blockIdx.y * 32;   // d base
    int tx = threadIdx.x & 31, ty = threadIdx.x >> 5;
    #pragma unroll
    for (int i = 0; i < 32; i += 8)
        tile[ty + i][tx] = in[(size_t)(bx + ty + i) * 1024 + by + tx];
    __syncthreads();
    #pragma unroll
    for (int i = 0; i < 32; i += 8)
        out[(size_t)(by + ty + i) * 2048 + bx + tx] = bf16r(tile[tx][ty + i]);
}

// ---------------------------------------------------------------- LayerNorm -> bf16
__global__ __launch_bounds__(256) void ln_kernel(const float* __restrict__ x,
                                                 const float* __restrict__ g,
                                                 const float* __restrict__ b,
                                                 ushort* __restrict__ xn) {
    int row = blockIdx.x;
    const float4* xr = (const float4*)(x + (size_t)row * D_MODEL);
    float4 v = xr[threadIdx.x];
    float s  = v.x + v.y + v.z + v.w;
    float ss = v.x*v.x + v.y*v.y + v.z*v.z + v.w*v.w;
    #pragma unroll
    for (int off = 32; off > 0; off >>= 1) {
        s  += __shfl_down(s,  off, 64);
        ss += __shfl_down(ss, off, 64);
    }
    __shared__ float rs[4], rss[4];
    int wave = threadIdx.x >> 6;
    if ((threadIdx.x & 63) == 0) { rs[wave] = s; rss[wave] = ss; }
    __syncthreads();
    s  = rs[0] + rs[1] + rs[2] + rs[3];
    ss = rss[0] + rss[1] + rss[2] + rss[3];
    float mu  = s * (1.f / D_MODEL);
    float var = ss * (1.f / D_MODEL) - mu * mu;
    float inv = rsqrtf(var + LN_EPS);
    float4 gv = ((const float4*)g)[threadIdx.x];
    float4 bv = ((const float4*)b)[threadIdx.x];
    ushort4 o;
    o.x = bf16r((v.x - mu) * inv * gv.x + bv.x);
    o.y = bf16r((v.y - mu) * inv * gv.y + bv.y);
    o.z = bf16r((v.z - mu) * inv * gv.z + bv.z);
    o.w = bf16r((v.w - mu) * inv * gv.w + bv.w);
    ((ushort4*)(xn + (size_t)row * D_MODEL))[threadIdx.x] = o;
}

// ------------------------------------------------- bf16 MFMA NT GEMM (m97-style)
// ACT=1: softplus(acc + bias[col]); RESID: += resid
template<int RESID, int ACT>
__global__ __launch_bounds__(256) void gemm_bt_bf16(
    const ushort* __restrict__ A, const ushort* __restrict__ B,
    float* __restrict__ C, int ldc, int K,
    const float* __restrict__ resid, const float* __restrict__ bias)
{
    __shared__ __align__(16) ushort As[128 * 32];   // [m][k] dense
    __shared__ __align__(16) ushort Bs[128 * 32];   // [n][k] dense
    int tid = threadIdx.x;
    int bm = blockIdx.x * 128, bn = blockIdx.y * 128;
    int wave = tid >> 6, lane = tid & 63;
    int wm = (wave & 1) * 64, wn = (wave >> 1) * 64;
    int quad = lane >> 4, m16 = lane & 15;
    int grow = tid >> 2;
    int gcol = (tid & 3) * 8;
    const size_t a0 = (size_t)(bm + grow) * K + gcol;
    const size_t b0 = (size_t)(bn + grow) * K + gcol;
    char* asw = (char*)As + wave * 1024;
    char* bsw = (char*)Bs + wave * 1024;

    f32x4 acc[4][4] = {};
    for (int k0 = 0; k0 < K; k0 += 32) {
        __builtin_amdgcn_global_load_lds((gp_t)(A + a0 + k0),                 (lp_t)asw,          16, 0, 0);
        __builtin_amdgcn_global_load_lds((gp_t)(A + a0 + (size_t)64*K + k0),  (lp_t)(asw + 4096), 16, 0, 0);
        __builtin_amdgcn_global_load_lds((gp_t)(B + b0 + k0),                 (lp_t)bsw,          16, 0, 0);
        __builtin_amdgcn_global_load_lds((gp_t)(B + b0 + (size_t)64*K + k0),  (lp_t)(bsw + 4096), 16, 0, 0);
        __syncthreads();
        short8 af[4], bf[4];
        #pragma unroll
        for (int i = 0; i < 4; ++i)
            af[i] = *(const short8*)&As[(wm + i * 16 + m16) * 32 + quad * 8];
        #pragma unroll
        for (int j = 0; j < 4; ++j)
            bf[j] = *(const short8*)&Bs[(wn + j * 16 + m16) * 32 + quad * 8];
        #pragma unroll
        for (int i = 0; i < 4; ++i)
            #pragma unroll
            for (int j = 0; j < 4; ++j)
                acc[i][j] = __builtin_amdgcn_mfma_f32_16x16x32_bf16(
                    af[i], bf[j], acc[i][j], 0, 0, 0);
        __syncthreads();
    }
    #pragma unroll
    for (int i = 0; i < 4; ++i) {
        #pragma unroll
        for (int r = 0; r < 4; ++r) {
            int row = bm + wm + i * 16 + quad * 4 + r;
            #pragma unroll
            for (int j = 0; j < 4; ++j) {
                int col = bn + wn + j * 16 + m16;
                float v = acc[i][j][r];
                if (ACT == 1) {
                    v += bias[col];
                    v = (v > 20.f) ? v : __logf(1.f + __expf(v));
                }
                if (RESID) v += resid[(size_t)row * ldc + col];
                C[(size_t)row * ldc + col] = v;
            }
        }
    }
}

// ---------------------------------------------------------------- scan v6
// Chunk-staged (32 t), double-buffered LDS, DPP reduction (no LDS red tile).
// Block 256 = 8 e x 32 s, grid 512. Gating fused at lane 31/63.
__global__ __launch_bounds__(256) void scan_kernel(
    const float* __restrict__ xz,     // [BT, 4224]  (x_ssm | z | dt_low,B,C)
    const float* __restrict__ dtm,    // [BT, 2048]
    const float* __restrict__ A_log_real,
    const float* __restrict__ A_imag,
    const float* __restrict__ D_param,
    ushort* __restrict__ y)           // [BT, 2048] bf16 (gated)
{
    const int tid  = threadIdx.x;
    const int s    = tid & 31;
    const int el   = tid >> 5;                 // 0..7
    const int b    = blockIdx.x >> 8;
    const int e0   = (blockIdx.x & 255) << 3;
    const int e    = e0 + el;
    const int sk   = tid & 7;                  // staging e
    const int stt  = tid >> 3;                 // staging t (0..31)
    const int brow = tid >> 4;                 // BC staging t row (0..15)
    const int bcp  = tid & 15;                 // BC col-pair idx

    __shared__ __align__(16) float dxp[2][8][17][4];  // [e][tp]{dt0,dtx0,dt1,dtx1}
    __shared__ __align__(16) float xzs[2][8][34][2];  // [e][t]{D*x, z*sig(z)}
    __shared__ __align__(16) float bcs[2][32][68];    // [t]{B0,C0,B1,C1,...}

    const float Ar2  = -__expf(A_log_real[e * D_STATE + s]) * 1.44269504f; // *log2e
    const float Ai2p = A_imag[e * D_STATE + s] * 0.15915494f;              // /(2*pi)
    const float Dps  = D_param[e0 + sk];
    float hr = 0.f, hi = 0.f;
    const float* xzb = xz + (size_t)b * 2048 * XZLD;
    const float* bcb = xzb + 4096 + DT_RANK;
    const float* dtb = dtm + (size_t)b * 2048 * 2048;
    ushort*      yb  = y   + (size_t)b * 2048 * 2048;

    float r_d, r_x, r_z;
    float2 rb0, rc0, rb1, rc1;
    {   // prologue: load + stage chunk 0
        r_d = dtb[(size_t)stt * 2048 + e0 + sk];
        r_x = xzb[(size_t)stt * XZLD + e0 + sk];
        r_z = xzb[(size_t)stt * XZLD + 2048 + e0 + sk];
        rb0 = *(const float2*)&bcb[(size_t)brow * XZLD + 2 * bcp];
        rc0 = *(const float2*)&bcb[(size_t)brow * XZLD + 32 + 2 * bcp];
        rb1 = *(const float2*)&bcb[(size_t)(brow + 16) * XZLD + 2 * bcp];
        rc1 = *(const float2*)&bcb[(size_t)(brow + 16) * XZLD + 32 + 2 * bcp];
        float dtx = r_d * r_x;
        float g   = r_z / (1.f + __expf(-r_z));
        float Dx  = Dps * r_x;
        *(float2*)&dxp[0][sk][stt >> 1][(stt & 1) * 2] = make_float2(r_d, dtx);
        *(float2*)&xzs[0][sk][stt]                     = make_float2(Dx, g);
        *(float4*)&bcs[0][brow][4 * bcp]      = make_float4(rb0.x, rc0.x, rb0.y, rc0.y);
        *(float4*)&bcs[0][brow + 16][4 * bcp] = make_float4(rb1.x, rc1.x, rb1.y, rc1.y);
    }
    for (int c = 0; c < 64; ++c) {
        const int buf = c & 1;
        __syncthreads();
        if (c < 63) {               // prefetch next chunk into registers
            const int tn = (c + 1) * 32;
            r_d = dtb[(size_t)(tn + stt) * 2048 + e0 + sk];
            r_x = xzb[(size_t)(tn + stt) * XZLD + e0 + sk];
            r_z = xzb[(size_t)(tn + stt) * XZLD + 2048 + e0 + sk];
            rb0 = *(const float2*)&bcb[(size_t)(tn + brow) * XZLD + 2 * bcp];
            rc0 = *(const float2*)&bcb[(size_t)(tn + brow) * XZLD + 32 + 2 * bcp];
            rb1 = *(const float2*)&bcb[(size_t)(tn + brow + 16) * XZLD + 2 * bcp];
            rc1 = *(const float2*)&bcb[(size_t)(tn + brow + 16) * XZLD + 32 + 2 * bcp];
        }
        #pragma unroll 4
        for (int tp = 0; tp < 16; ++tp) {
            float4 dd  = *(const float4*)&dxp[buf][el][tp][0];     // broadcast
            float2 bc0 = *(const float2*)&bcs[buf][2 * tp][2 * s];
            float2 bc1 = *(const float2*)&bcs[buf][2 * tp + 1][2 * s];
            // t = 2*tp
            float sc = __builtin_amdgcn_exp2f(Ar2 * dd.x);
            float u  = Ai2p * dd.x;
            float sa = __builtin_amdgcn_sinf(u), ca = __builtin_amdgcn_cosf(u);
            float dAr = sc * ca, dAi = sc * sa;
            float hrn = fmaf(dAr, hr, fmaf(-dAi, hi, dd.y * bc0.x));
            hi = fmaf(dAr, hi, dAi * hr); hr = hrn;
            float p0 = hr * bc0.y;
            // t = 2*tp+1
            sc = __builtin_amdgcn_exp2f(Ar2 * dd.z);
            u  = Ai2p * dd.z;
            sa = __builtin_amdgcn_sinf(u); ca = __builtin_amdgcn_cosf(u);
            dAr = sc * ca; dAi = sc * sa;
            hrn = fmaf(dAr, hr, fmaf(-dAi, hi, dd.w * bc1.x));
            hi = fmaf(dAr, hi, dAi * hr); hr = hrn;
            float p1 = hr * bc1.y;
            // cross-lane sums (VALU pipe); lanes 31/63 hold results
            p0 = dpp_red32(p0);
            p1 = dpp_red32(p1);
            if (s == 31) {
                float4 xg = *(const float4*)&xzs[buf][el][2 * tp]; // {Dx0,g0,Dx1,g1}
                yb[(size_t)(c * 32 + 2 * tp) * 2048 + e]     = bf16r((p0 + xg.x) * xg.y);
                yb[(size_t)(c * 32 + 2 * tp + 1) * 2048 + e] = bf16r((p1 + xg.z) * xg.w);
            }
        }
        if (c < 63) {
            const int nb = buf ^ 1;
            float dtx = r_d * r_x;
            float g   = r_z / (1.f + __expf(-r_z));
            float Dx  = Dps * r_x;
            *(float2*)&dxp[nb][sk][stt >> 1][(stt & 1) * 2] = make_float2(r_d, dtx);
            *(float2*)&xzs[nb][sk][stt]                     = make_float2(Dx, g);
            *(float4*)&bcs[nb][brow][4 * bcp]      = make_float4(rb0.x, rc0.x, rb0.y, rc0.y);
            *(float4*)&bcs[nb][brow + 16][4 * bcp] = make_float4(rb1.x, rc1.x, rb1.y, rc1.y);
        }
    }
}

// ---------------------------------------------------------------- launch
extern "C" void kernel_launch(void* const* d_in, const int* in_sizes, int n_in,
                              void* d_out, int out_size, void* d_ws, size_t ws_size,
                              hipStream_t stream) {
    const float* x          = (const float*)d_in[0];
    const float* W_in       = (const float*)d_in[1];
    const float* W_x        = (const float*)d_in[2];
    const float* W_dt       = (const float*)d_in[3];
    const float* b_dt       = (const float*)d_in[4];
    const float* A_log_real = (const float*)d_in[5];
    const float* A_imag     = (const float*)d_in[6];
    const float* D_param    = (const float*)d_in[7];
    const float* W_out      = (const float*)d_in[8];
    const float* ln_g       = (const float*)d_in[9];
    const float* ln_b       = (const float*)d_in[10];
    float* out = (float*)d_out;

    char* ws = (char*)d_ws;
    float*  xz       = (float*) (ws);                        // 66 MiB [4096,4224]
    float*  dt       = (float*) (ws + ((size_t) 66 << 20));  // 32 MiB [4096,2048]
    ushort* xn_bf    = (ushort*)(ws + ((size_t) 98 << 20));  //  8 MiB [4096,1024]
    ushort* Waug     = (ushort*)(ws + ((size_t)106 << 20));  //  8.25 MiB [4224,1024]
    ushort* y_bf     = (ushort*)(ws + ((size_t)115 << 20));  // 16 MiB [4096,2048]
    ushort* Wout_bf  = (ushort*)(ws + ((size_t)131 << 20));  //  4 MiB [1024,2048]
    ushort* Wdt_bf   = (ushort*)(ws + ((size_t)135 << 20));  //  0.25 MiB [2048,64]
    ushort* dtlow_bf = (ushort*)(ws + ((size_t)136 << 20));  //  0.5 MiB [4096,64]
    // transient prep buffers inside xz region (dead before GEMM1 writes xz)
    float*  Wcomb   = (float*) (ws);                         // 0.5 MiB [128,1024]
    ushort* Wx_bf   = (ushort*)(ws + ((size_t)  1 << 20));   // 0.5 MiB [128,2048]
    ushort* WinT_bf = (ushort*)(ws + ((size_t)  2 << 20));   //  4 MiB [1024,2048]

    // --- weight prep ---
    cvt_bf16<<<4096, 256, 0, stream>>>(W_in,  Waug,    4096*1024/4);
    cvt_bf16<<<2048, 256, 0, stream>>>(W_out, Wout_bf, 1024*2048/4);
    cvt_bf16<<< 256, 256, 0, stream>>>(W_x,   Wx_bf,    128*2048/4);
    cvt_bf16<<< 128, 256, 0, stream>>>(W_dt,  Wdt_bf,   2048*64/4);
    transpose_cvt<<<dim3(64, 32), 256, 0, stream>>>(W_in, WinT_bf);
    // W_comb = W_x @ W_in_x  [128,1024]
    gemm_bt_bf16<0,0><<<dim3(1, 8), 256, 0, stream>>>(
        Wx_bf, WinT_bf, Wcomb, 1024, 2048, nullptr, nullptr);
    cvt_bf16<<<128, 256, 0, stream>>>(Wcomb, Waug + (size_t)4096*1024, 128*1024/4);
    // --- main chain ---
    ln_kernel<<<BT, 256, 0, stream>>>(x, ln_g, ln_b, xn_bf);
    // GEMM1(aug): xz_aug = xn @ [W_in; W_comb]^T   [4096,4224]
    gemm_bt_bf16<0,0><<<dim3(BT/128, XZLD/128), 256, 0, stream>>>(
        xn_bf, Waug, xz, XZLD, D_MODEL, nullptr, nullptr);
    // dt_low -> bf16 dense [4096,64]
    cvt_dtlow<<<256, 256, 0, stream>>>(xz, dtlow_bf);
    // GEMM3 (MFMA): dt = softplus(dt_low @ W_dt^T + b_dt)  [4096,2048]
    gemm_bt_bf16<0,1><<<dim3(BT/128, D_INNER/128), 256, 0, stream>>>(
        dtlow_bf, Wdt_bf, dt, D_INNER, DT_RANK, nullptr, b_dt);
    // scan + fused gating -> y (bf16)
    scan_kernel<<<512, 256, 0, stream>>>(xz, dt, A_log_real, A_imag, D_param, y_bf);
    // GEMM4: out = residual + y @ W_out^T   [4096,1024]
    gemm_bt_bf16<1,0><<<dim3(BT/128, D_MODEL/128), 256, 0, stream>>>(
        y_bf, Wout_bf, out, D_MODEL, D_INNER, x, nullptr);
}

// Round 7
// 501.729 us; speedup vs baseline: 1.1005x; 1.1005x over previous
//
#include <hip/hip_runtime.h>
#include <math.h>

#define D_MODEL 1024
#define D_STATE 32
#define D_INNER 2048
#define DT_RANK 64
#define BT 4096            // B*T = 2*2048
#define XZLD 4224          // xz_aug row stride (4096 + 128)
#define LN_EPS 1e-5f

typedef __attribute__((ext_vector_type(8))) short short8;
typedef __attribute__((ext_vector_type(4))) float f32x4;
typedef const __attribute__((address_space(1))) void* gp_t;
typedef __attribute__((address_space(3))) void* lp_t;

__device__ __forceinline__ ushort bf16r(float f) {
    unsigned u = __float_as_uint(f);
    u += 0x7fff + ((u >> 16) & 1);          // round-to-nearest-even
    return (ushort)(u >> 16);
}

// 16-lane (DPP row) partial sum; row sums land in lanes 15/31/47/63.
__device__ __forceinline__ float dpp_red16(float x) {
    int t;
    t = __builtin_amdgcn_update_dpp(0, __float_as_int(x), 0x111, 0xf, 0xf, true); // row_shr:1
    x += __int_as_float(t);
    t = __builtin_amdgcn_update_dpp(0, __float_as_int(x), 0x112, 0xf, 0xf, true); // row_shr:2
    x += __int_as_float(t);
    t = __builtin_amdgcn_update_dpp(0, __float_as_int(x), 0x114, 0xf, 0xf, true); // row_shr:4
    x += __int_as_float(t);
    t = __builtin_amdgcn_update_dpp(0, __float_as_int(x), 0x118, 0xf, 0xf, true); // row_shr:8
    x += __int_as_float(t);
    return x;
}

// --------------------------------------------- fused weight conversions (1 kernel)
__global__ __launch_bounds__(256) void prep_weights(
    const float* __restrict__ W_in, const float* __restrict__ W_out,
    const float* __restrict__ W_dt, const float* __restrict__ W_x,
    ushort* __restrict__ Waug, ushort* __restrict__ Wout_bf,
    ushort* __restrict__ Wdt_bf, ushort* __restrict__ Wx_bf) {
    int bid = blockIdx.x;
    const float* src; ushort* dst; int i;
    if (bid < 4096)      { src = W_in;  dst = Waug;    i = bid * 256 + threadIdx.x; }
    else if (bid < 6144) { src = W_out; dst = Wout_bf; i = (bid - 4096) * 256 + threadIdx.x; }
    else if (bid < 6400) { src = W_x;   dst = Wx_bf;   i = (bid - 6144) * 256 + threadIdx.x; }
    else                 { src = W_dt;  dst = Wdt_bf;  i = (bid - 6400) * 256 + threadIdx.x; }
    float4 v = ((const float4*)src)[i];
    ushort4 o;
    o.x = bf16r(v.x); o.y = bf16r(v.y); o.z = bf16r(v.z); o.w = bf16r(v.w);
    ((ushort4*)dst)[i] = o;
}

// ------------------------------------------- dt_low cols of xz_aug -> bf16 dense
__global__ __launch_bounds__(256) void cvt_dtlow(const float* __restrict__ xz,
                                                 ushort* __restrict__ out) {
    int i = blockIdx.x * 256 + threadIdx.x;   // 0 .. 65536
    int row = i >> 4, c = (i & 15) << 2;
    float4 v = *(const float4*)&xz[(size_t)row * XZLD + 4096 + c];
    ushort4 o;
    o.x = bf16r(v.x); o.y = bf16r(v.y); o.z = bf16r(v.z); o.w = bf16r(v.w);
    ((ushort4*)out)[i] = o;
}

// ---------------------------------------------------------------- transpose + cvt
// in: fp32 [2048,1024] -> out: bf16 [1024,2048]
__global__ __launch_bounds__(256) void transpose_cvt(const float* __restrict__ in,
                                                     ushort* __restrict__ out) {
    __shared__ float tile[32][33];
    int bx = blockIdx.x * 32;   // e base
    int by = blockIdx.y * 32;   // d base
    int tx = threadIdx.x & 31, ty = threadIdx.x >> 5;
    #pragma unroll
    for (int i = 0; i < 32; i += 8)
        tile[ty + i][tx] = in[(size_t)(bx + ty + i) * 1024 + by + tx];
    __syncthreads();
    #pragma unroll
    for (int i = 0; i < 32; i += 8)
        out[(size_t)(by + ty + i) * 2048 + bx + tx] = bf16r(tile[tx][ty + i]);
}

// ---------------------------------------------------------------- LayerNorm -> bf16
__global__ __launch_bounds__(256) void ln_kernel(const float* __restrict__ x,
                                                 const float* __restrict__ g,
                                                 const float* __restrict__ b,
                                                 ushort* __restrict__ xn) {
    int row = blockIdx.x;
    const float4* xr = (const float4*)(x + (size_t)row * D_MODEL);
    float4 v = xr[threadIdx.x];
    float s  = v.x + v.y + v.z + v.w;
    float ss = v.x*v.x + v.y*v.y + v.z*v.z + v.w*v.w;
    #pragma unroll
    for (int off = 32; off > 0; off >>= 1) {
        s  += __shfl_down(s,  off, 64);
        ss += __shfl_down(ss, off, 64);
    }
    __shared__ float rs[4], rss[4];
    int wave = threadIdx.x >> 6;
    if ((threadIdx.x & 63) == 0) { rs[wave] = s; rss[wave] = ss; }
    __syncthreads();
    s  = rs[0] + rs[1] + rs[2] + rs[3];
    ss = rss[0] + rss[1] + rss[2] + rss[3];
    float mu  = s * (1.f / D_MODEL);
    float var = ss * (1.f / D_MODEL) - mu * mu;
    float inv = rsqrtf(var + LN_EPS);
    float4 gv = ((const float4*)g)[threadIdx.x];
    float4 bv = ((const float4*)b)[threadIdx.x];
    ushort4 o;
    o.x = bf16r((v.x - mu) * inv * gv.x + bv.x);
    o.y = bf16r((v.y - mu) * inv * gv.y + bv.y);
    o.z = bf16r((v.z - mu) * inv * gv.z + bv.z);
    o.w = bf16r((v.w - mu) * inv * gv.w + bv.w);
    ((ushort4*)(xn + (size_t)row * D_MODEL))[threadIdx.x] = o;
}

// ------------------------------------------------- bf16 MFMA NT GEMM (m97-style)
// ACT=1: softplus(acc + bias[col]); RESID: += resid; OBF=1: bf16 output.
template<int RESID, int ACT, int OBF>
__global__ __launch_bounds__(256) void gemm_bt_bf16(
    const ushort* __restrict__ A, const ushort* __restrict__ B,
    void* __restrict__ Cv, int ldc, int K,
    const float* __restrict__ resid, const float* __restrict__ bias)
{
    __shared__ __align__(16) ushort As[128 * 32];   // [m][k] dense
    __shared__ __align__(16) ushort Bs[128 * 32];   // [n][k] dense
    int tid = threadIdx.x;
    int bm = blockIdx.x * 128, bn = blockIdx.y * 128;
    int wave = tid >> 6, lane = tid & 63;
    int wm = (wave & 1) * 64, wn = (wave >> 1) * 64;
    int quad = lane >> 4, m16 = lane & 15;
    int grow = tid >> 2;
    int gcol = (tid & 3) * 8;
    const size_t a0 = (size_t)(bm + grow) * K + gcol;
    const size_t b0 = (size_t)(bn + grow) * K + gcol;
    char* asw = (char*)As + wave * 1024;
    char* bsw = (char*)Bs + wave * 1024;

    f32x4 acc[4][4] = {};
    for (int k0 = 0; k0 < K; k0 += 32) {
        __builtin_amdgcn_global_load_lds((gp_t)(A + a0 + k0),                 (lp_t)asw,          16, 0, 0);
        __builtin_amdgcn_global_load_lds((gp_t)(A + a0 + (size_t)64*K + k0),  (lp_t)(asw + 4096), 16, 0, 0);
        __builtin_amdgcn_global_load_lds((gp_t)(B + b0 + k0),                 (lp_t)bsw,          16, 0, 0);
        __builtin_amdgcn_global_load_lds((gp_t)(B + b0 + (size_t)64*K + k0),  (lp_t)(bsw + 4096), 16, 0, 0);
        __syncthreads();
        short8 af[4], bf[4];
        #pragma unroll
        for (int i = 0; i < 4; ++i)
            af[i] = *(const short8*)&As[(wm + i * 16 + m16) * 32 + quad * 8];
        #pragma unroll
        for (int j = 0; j < 4; ++j)
            bf[j] = *(const short8*)&Bs[(wn + j * 16 + m16) * 32 + quad * 8];
        #pragma unroll
        for (int i = 0; i < 4; ++i)
            #pragma unroll
            for (int j = 0; j < 4; ++j)
                acc[i][j] = __builtin_amdgcn_mfma_f32_16x16x32_bf16(
                    af[i], bf[j], acc[i][j], 0, 0, 0);
        __syncthreads();
    }
    #pragma unroll
    for (int i = 0; i < 4; ++i) {
        #pragma unroll
        for (int r = 0; r < 4; ++r) {
            int row = bm + wm + i * 16 + quad * 4 + r;
            #pragma unroll
            for (int j = 0; j < 4; ++j) {
                int col = bn + wn + j * 16 + m16;
                float v = acc[i][j][r];
                if (ACT == 1) {
                    v += bias[col];
                    v = (v > 20.f) ? v : __logf(1.f + __expf(v));
                }
                if (RESID) v += resid[(size_t)row * ldc + col];
                if (OBF) ((ushort*)Cv)[(size_t)row * ldc + col] = bf16r(v);
                else     ((float*) Cv)[(size_t)row * ldc + col] = v;
            }
        }
    }
}

// ---------------------------------------------------------------- scan v7
// Chunk-staged (32 t), double-buffered LDS. Block 256 = 8 e x 32 s, grid 512.
// Hybrid reduce: 4-step DPP 16-lane partials + tiny LDS pp tile. Packed
// {B0,C0,B1,C1} b128 per 2t. Gating fused at chunk end (full-wave store).
__global__ __launch_bounds__(256) void scan_kernel(
    const float* __restrict__ xz,     // [BT, 4224]  (x_ssm | z | dt_low,B,C)
    const float* __restrict__ dtm,    // [BT, 2048]
    const float* __restrict__ A_log_real,
    const float* __restrict__ A_imag,
    const float* __restrict__ D_param,
    ushort* __restrict__ y)           // [BT, 2048] bf16 (gated)
{
    const int tid  = threadIdx.x;
    const int lane = tid & 63;
    const int s    = tid & 31;
    const int elb  = tid >> 5;                 // 0..7
    const int b    = blockIdx.x >> 8;
    const int e0   = (blockIdx.x & 255) << 3;
    const int e    = e0 + elb;
    const int stt  = tid >> 3, sk  = tid & 7;  // dxz/xzs staging: t, e
    const int btp  = tid >> 4, bsp = tid & 15; // bc staging: t-pair, s-pair
    const int q    = (lane >> 4) & 1;          // which 16-lane partial

    __shared__ __align__(16) float dxp[2][8][17][4];  // [e][tp]{dt0,dtx0,dt1,dtx1}
    __shared__ __align__(16) float xzs[2][8][34][2];  // [e][t]{D*x, z*sig(z)}
    __shared__ __align__(16) float bcs[2][16][33][4]; // [tp][s]{B0,C0,B1,C1}
    __shared__ __align__(16) float pp[8][2][32];      // [e][half][t] partials

    const float Ar2  = -__expf(A_log_real[e * D_STATE + s]) * 1.44269504f; // *log2e
    const float Ai2p = A_imag[e * D_STATE + s] * 0.15915494f;              // /(2*pi)
    const float Dps  = D_param[e0 + sk];
    float hr = 0.f, hi = 0.f;
    const float* xzb = xz + (size_t)b * 2048 * XZLD;
    const float* bcb = xzb + 4096 + DT_RANK;
    const float* dtb = dtm + (size_t)b * 2048 * 2048;
    ushort*      yb  = y   + (size_t)b * 2048 * 2048;

    float r_d, r_x, r_z;
    float2 rB0, rC0, rB1, rC1;

#define LOADC(T0) do {                                                        \
    r_d = dtb[(size_t)((T0) + stt) * 2048 + e0 + sk];                         \
    r_x = xzb[(size_t)((T0) + stt) * XZLD + e0 + sk];                         \
    r_z = xzb[(size_t)((T0) + stt) * XZLD + 2048 + e0 + sk];                  \
    rB0 = *(const float2*)&bcb[(size_t)((T0) + 2*btp) * XZLD + 2*bsp];        \
    rC0 = *(const float2*)&bcb[(size_t)((T0) + 2*btp) * XZLD + 32 + 2*bsp];   \
    rB1 = *(const float2*)&bcb[(size_t)((T0) + 2*btp+1) * XZLD + 2*bsp];      \
    rC1 = *(const float2*)&bcb[(size_t)((T0) + 2*btp+1) * XZLD + 32 + 2*bsp]; \
  } while (0)

#define STAGE(NB) do {                                                        \
    float dtx = r_d * r_x;                                                    \
    float gg  = r_z / (1.f + __expf(-r_z));                                   \
    float Dx  = Dps * r_x;                                                    \
    *(float2*)&dxp[NB][sk][stt >> 1][(stt & 1) * 2] = make_float2(r_d, dtx);  \
    *(float2*)&xzs[NB][sk][stt] = make_float2(Dx, gg);                        \
    *(float4*)&bcs[NB][btp][2*bsp][0]   = make_float4(rB0.x, rC0.x, rB1.x, rC1.x); \
    *(float4*)&bcs[NB][btp][2*bsp+1][0] = make_float4(rB0.y, rC0.y, rB1.y, rC1.y); \
  } while (0)

    LOADC(0);
    STAGE(0);
    for (int c = 0; c < 64; ++c) {
        const int buf = c & 1;
        __syncthreads();
        if (c < 63) LOADC((c + 1) * 32);
        #pragma unroll
        for (int tp = 0; tp < 16; ++tp) {
            float4 dd = *(const float4*)&dxp[buf][elb][tp][0];   // broadcast
            float4 bc = *(const float4*)&bcs[buf][tp][s][0];
            // t = 2*tp
            float sc = __builtin_amdgcn_exp2f(Ar2 * dd.x);
            float u  = Ai2p * dd.x;
            float sa = __builtin_amdgcn_sinf(u), ca = __builtin_amdgcn_cosf(u);
            float dAr = sc * ca, dAi = sc * sa;
            float hrn = fmaf(dAr, hr, fmaf(-dAi, hi, dd.y * bc.x));
            hi = fmaf(dAr, hi, dAi * hr); hr = hrn;
            float p0 = hr * bc.y;
            // t = 2*tp+1
            sc = __builtin_amdgcn_exp2f(Ar2 * dd.z);
            u  = Ai2p * dd.z;
            sa = __builtin_amdgcn_sinf(u); ca = __builtin_amdgcn_cosf(u);
            dAr = sc * ca; dAi = sc * sa;
            hrn = fmaf(dAr, hr, fmaf(-dAi, hi, dd.w * bc.z));
            hi = fmaf(dAr, hi, dAi * hr); hr = hrn;
            float p1 = hr * bc.w;
            // 16-lane partial sums on VALU; lanes 15/31/47/63 hold them
            p0 = dpp_red16(p0);
            p1 = dpp_red16(p1);
            if ((lane & 15) == 15)
                *(float2*)&pp[elb][q][2 * tp] = make_float2(p0, p1);
        }
        // wave-private, in-order DS pipe: no barrier needed
        float pA = pp[elb][0][s];
        float pB = pp[elb][1][s];
        float2 xg = *(const float2*)&xzs[buf][elb][s];   // {D*x, z*sig(z)} at t=s
        yb[(size_t)(c * 32 + s) * 2048 + e] = bf16r((pA + pB + xg.x) * xg.y);
        if (c < 63) STAGE(buf ^ 1);
    }
#undef LOADC
#undef STAGE
}

// ---------------------------------------------------------------- launch
extern "C" void kernel_launch(void* const* d_in, const int* in_sizes, int n_in,
                              void* d_out, int out_size, void* d_ws, size_t ws_size,
                              hipStream_t stream) {
    const float* x          = (const float*)d_in[0];
    const float* W_in       = (const float*)d_in[1];
    const float* W_x        = (const float*)d_in[2];
    const float* W_dt       = (const float*)d_in[3];
    const float* b_dt       = (const float*)d_in[4];
    const float* A_log_real = (const float*)d_in[5];
    const float* A_imag     = (const float*)d_in[6];
    const float* D_param    = (const float*)d_in[7];
    const float* W_out      = (const float*)d_in[8];
    const float* ln_g       = (const float*)d_in[9];
    const float* ln_b       = (const float*)d_in[10];
    float* out = (float*)d_out;

    char* ws = (char*)d_ws;
    float*  xz       = (float*) (ws);                        // 66 MiB [4096,4224]
    float*  dt       = (float*) (ws + ((size_t) 66 << 20));  // 32 MiB [4096,2048]
    ushort* xn_bf    = (ushort*)(ws + ((size_t) 98 << 20));  //  8 MiB [4096,1024]
    ushort* Waug     = (ushort*)(ws + ((size_t)106 << 20));  //  8.25 MiB [4224,1024]
    ushort* y_bf     = (ushort*)(ws + ((size_t)115 << 20));  // 16 MiB [4096,2048]
    ushort* Wout_bf  = (ushort*)(ws + ((size_t)131 << 20));  //  4 MiB [1024,2048]
    ushort* Wdt_bf   = (ushort*)(ws + ((size_t)135 << 20));  //  0.25 MiB [2048,64]
    ushort* dtlow_bf = (ushort*)(ws + ((size_t)136 << 20));  //  0.5 MiB [4096,64]
    // transient prep buffers inside xz region (dead before GEMM1 writes xz)
    ushort* Wx_bf   = (ushort*)(ws + ((size_t)  1 << 20));   // 0.5 MiB [128,2048]
    ushort* WinT_bf = (ushort*)(ws + ((size_t)  2 << 20));   //  4 MiB [1024,2048]

    // --- weight prep (3 dispatches) ---
    prep_weights<<<6528, 256, 0, stream>>>(W_in, W_out, W_dt, W_x,
                                           Waug, Wout_bf, Wdt_bf, Wx_bf);
    transpose_cvt<<<dim3(64, 32), 256, 0, stream>>>(W_in, WinT_bf);
    // W_comb = W_x @ W_in_x -> bf16 directly into Waug rows 4096..4223
    gemm_bt_bf16<0,0,1><<<dim3(1, 8), 256, 0, stream>>>(
        Wx_bf, WinT_bf, Waug + (size_t)4096 * 1024, 1024, 2048, nullptr, nullptr);
    // --- main chain ---
    ln_kernel<<<BT, 256, 0, stream>>>(x, ln_g, ln_b, xn_bf);
    // GEMM1(aug): xz_aug = xn @ [W_in; W_comb]^T   [4096,4224]
    gemm_bt_bf16<0,0,0><<<dim3(BT/128, XZLD/128), 256, 0, stream>>>(
        xn_bf, Waug, xz, XZLD, D_MODEL, nullptr, nullptr);
    // dt_low -> bf16 dense [4096,64]
    cvt_dtlow<<<256, 256, 0, stream>>>(xz, dtlow_bf);
    // GEMM3 (MFMA): dt = softplus(dt_low @ W_dt^T + b_dt)  [4096,2048]
    gemm_bt_bf16<0,1,0><<<dim3(BT/128, D_INNER/128), 256, 0, stream>>>(
        dtlow_bf, Wdt_bf, dt, D_INNER, DT_RANK, nullptr, b_dt);
    // scan + fused gating -> y (bf16)
    scan_kernel<<<512, 256, 0, stream>>>(xz, dt, A_log_real, A_imag, D_param, y_bf);
    // GEMM4: out = residual + y @ W_out^T   [4096,1024]
    gemm_bt_bf16<1,0,0><<<dim3(BT/128, D_MODEL/128), 256, 0, stream>>>(
        y_bf, Wout_bf, out, D_MODEL, D_INNER, x, nullptr);
}

// Round 8
// 497.510 us; speedup vs baseline: 1.1098x; 1.0085x over previous
//
#include <hip/hip_runtime.h>
#include <math.h>

#define D_MODEL 1024
#define D_STATE 32
#define D_INNER 2048
#define DT_RANK 64
#define BT 4096            // B*T = 2*2048
#define LN_EPS 1e-5f

typedef __attribute__((ext_vector_type(8))) short short8;
typedef __attribute__((ext_vector_type(4))) float f32x4;
typedef const __attribute__((address_space(1))) void* gp_t;
typedef __attribute__((address_space(3))) void* lp_t;

__device__ __forceinline__ ushort bf16r(float f) {
    unsigned u = __float_as_uint(f);
    u += 0x7fff + ((u >> 16) & 1);          // round-to-nearest-even
    return (ushort)(u >> 16);
}
__device__ __forceinline__ float bflo(unsigned u) { return __uint_as_float(u << 16); }
__device__ __forceinline__ float bfhi(unsigned u) { return __uint_as_float(u & 0xffff0000u); }

// 16-lane (DPP row) partial sum; row sums land in lanes 15/31/47/63.
__device__ __forceinline__ float dpp_red16(float x) {
    int t;
    t = __builtin_amdgcn_update_dpp(0, __float_as_int(x), 0x111, 0xf, 0xf, true);
    x += __int_as_float(t);
    t = __builtin_amdgcn_update_dpp(0, __float_as_int(x), 0x112, 0xf, 0xf, true);
    x += __int_as_float(t);
    t = __builtin_amdgcn_update_dpp(0, __float_as_int(x), 0x114, 0xf, 0xf, true);
    x += __int_as_float(t);
    t = __builtin_amdgcn_update_dpp(0, __float_as_int(x), 0x118, 0xf, 0xf, true);
    x += __int_as_float(t);
    return x;
}

// ----------------------------- fused weight conversions + W_in transpose
__global__ __launch_bounds__(256) void prep_weights(
    const float* __restrict__ W_in, const float* __restrict__ W_out,
    const float* __restrict__ W_dt, const float* __restrict__ W_x,
    ushort* __restrict__ Waug, ushort* __restrict__ Wout_bf,
    ushort* __restrict__ Wdt_bf, ushort* __restrict__ Wx_bf,
    ushort* __restrict__ WinT_bf) {
    __shared__ float tile[32][33];
    int bid = blockIdx.x;
    if (bid < 6528) {
        const float* src; ushort* dst; int i;
        if (bid < 4096)      { src = W_in;  dst = Waug;    i = bid * 256 + threadIdx.x; }
        else if (bid < 6144) { src = W_out; dst = Wout_bf; i = (bid - 4096) * 256 + threadIdx.x; }
        else if (bid < 6400) { src = W_x;   dst = Wx_bf;   i = (bid - 6144) * 256 + threadIdx.x; }
        else                 { src = W_dt;  dst = Wdt_bf;  i = (bid - 6400) * 256 + threadIdx.x; }
        float4 v = ((const float4*)src)[i];
        ushort4 o;
        o.x = bf16r(v.x); o.y = bf16r(v.y); o.z = bf16r(v.z); o.w = bf16r(v.w);
        ((ushort4*)dst)[i] = o;
    } else {
        // transpose W_in [2048,1024] -> WinT [1024,2048] bf16 (x_ssm half)
        int bid2 = bid - 6528;
        int bx = (bid2 & 63) * 32;   // e base
        int by = (bid2 >> 6) * 32;   // d base
        int tx = threadIdx.x & 31, ty = threadIdx.x >> 5;
        #pragma unroll
        for (int i = 0; i < 32; i += 8)
            tile[ty + i][tx] = W_in[(size_t)(bx + ty + i) * 1024 + by + tx];
        __syncthreads();
        #pragma unroll
        for (int i = 0; i < 32; i += 8)
            WinT_bf[(size_t)(by + ty + i) * 2048 + bx + tx] = bf16r(tile[tx][ty + i]);
    }
}

// ---------------------------------------------------------------- LayerNorm -> bf16
__global__ __launch_bounds__(256) void ln_kernel(const float* __restrict__ x,
                                                 const float* __restrict__ g,
                                                 const float* __restrict__ b,
                                                 ushort* __restrict__ xn) {
    int row = blockIdx.x;
    const float4* xr = (const float4*)(x + (size_t)row * D_MODEL);
    float4 v = xr[threadIdx.x];
    float s  = v.x + v.y + v.z + v.w;
    float ss = v.x*v.x + v.y*v.y + v.z*v.z + v.w*v.w;
    #pragma unroll
    for (int off = 32; off > 0; off >>= 1) {
        s  += __shfl_down(s,  off, 64);
        ss += __shfl_down(ss, off, 64);
    }
    __shared__ float rs[4], rss[4];
    int wave = threadIdx.x >> 6;
    if ((threadIdx.x & 63) == 0) { rs[wave] = s; rss[wave] = ss; }
    __syncthreads();
    s  = rs[0] + rs[1] + rs[2] + rs[3];
    ss = rss[0] + rss[1] + rss[2] + rss[3];
    float mu  = s * (1.f / D_MODEL);
    float var = ss * (1.f / D_MODEL) - mu * mu;
    float inv = rsqrtf(var + LN_EPS);
    float4 gv = ((const float4*)g)[threadIdx.x];
    float4 bv = ((const float4*)b)[threadIdx.x];
    ushort4 o;
    o.x = bf16r((v.x - mu) * inv * gv.x + bv.x);
    o.y = bf16r((v.y - mu) * inv * gv.y + bv.y);
    o.z = bf16r((v.z - mu) * inv * gv.z + bv.z);
    o.w = bf16r((v.w - mu) * inv * gv.w + bv.w);
    ((ushort4*)(xn + (size_t)row * D_MODEL))[threadIdx.x] = o;
}

// ------------------------------------------------- bf16 MFMA NT GEMM 128x128
// MODE 0: fp32 C out. MODE 1: bf16 C out. MODE 2 (GEMM1 scan-pack): cols
// <2048 -> x bf16 into xg[slot].lo; <4096 -> g=z*sig(z) into xg[slot].hi;
// <4160 -> dtlow_bf; else bc_bf. MODE 3 (GEMM3): softplus(+bias) -> dtp
// packed fp32 [b][eg][t][8].
template<int MODE>
__global__ __launch_bounds__(256) void gemm_bt_bf16(
    const ushort* __restrict__ A, const ushort* __restrict__ B,
    float* __restrict__ C, int ldc, int K,
    const float* __restrict__ resid, const float* __restrict__ bias,
    ushort* __restrict__ xg16, ushort* __restrict__ dtlow_bf,
    ushort* __restrict__ bc_bf, float* __restrict__ dtp)
{
    __shared__ __align__(16) ushort As[128 * 32];   // [m][k] dense
    __shared__ __align__(16) ushort Bs[128 * 32];   // [n][k] dense
    int tid = threadIdx.x;
    int bm = blockIdx.x * 128, bn = blockIdx.y * 128;
    int wave = tid >> 6, lane = tid & 63;
    int wm = (wave & 1) * 64, wn = (wave >> 1) * 64;
    int quad = lane >> 4, m16 = lane & 15;
    int grow = tid >> 2;
    int gcol = (tid & 3) * 8;
    const size_t a0 = (size_t)(bm + grow) * K + gcol;
    const size_t b0 = (size_t)(bn + grow) * K + gcol;
    char* asw = (char*)As + wave * 1024;
    char* bsw = (char*)Bs + wave * 1024;

    f32x4 acc[4][4] = {};
    for (int k0 = 0; k0 < K; k0 += 32) {
        __builtin_amdgcn_global_load_lds((gp_t)(A + a0 + k0),                 (lp_t)asw,          16, 0, 0);
        __builtin_amdgcn_global_load_lds((gp_t)(A + a0 + (size_t)64*K + k0),  (lp_t)(asw + 4096), 16, 0, 0);
        __builtin_amdgcn_global_load_lds((gp_t)(B + b0 + k0),                 (lp_t)bsw,          16, 0, 0);
        __builtin_amdgcn_global_load_lds((gp_t)(B + b0 + (size_t)64*K + k0),  (lp_t)(bsw + 4096), 16, 0, 0);
        __syncthreads();
        short8 af[4], bf[4];
        #pragma unroll
        for (int i = 0; i < 4; ++i)
            af[i] = *(const short8*)&As[(wm + i * 16 + m16) * 32 + quad * 8];
        #pragma unroll
        for (int j = 0; j < 4; ++j)
            bf[j] = *(const short8*)&Bs[(wn + j * 16 + m16) * 32 + quad * 8];
        #pragma unroll
        for (int i = 0; i < 4; ++i)
            #pragma unroll
            for (int j = 0; j < 4; ++j)
                acc[i][j] = __builtin_amdgcn_mfma_f32_16x16x32_bf16(
                    af[i], bf[j], acc[i][j], 0, 0, 0);
        __syncthreads();
    }
    #pragma unroll
    for (int i = 0; i < 4; ++i) {
        #pragma unroll
        for (int r = 0; r < 4; ++r) {
            int row = bm + wm + i * 16 + quad * 4 + r;
            #pragma unroll
            for (int j = 0; j < 4; ++j) {
                int col = bn + wn + j * 16 + m16;
                float v = acc[i][j][r];
                if (MODE == 0) {
                    C[(size_t)row * ldc + col] = v;
                } else if (MODE == 1) {
                    ((ushort*)C)[(size_t)row * ldc + col] = bf16r(v);
                } else if (MODE == 2) {
                    int bb = row >> 11, t = row & 2047;
                    if (col < 2048) {
                        size_t slot = ((size_t)(bb * 256 + (col >> 3)) * 2048 + t) * 8 + (col & 7);
                        xg16[slot * 2] = bf16r(v);
                    } else if (col < 4096) {
                        int e2 = col - 2048;
                        float gg = v / (1.f + __expf(-v));
                        size_t slot = ((size_t)(bb * 256 + (e2 >> 3)) * 2048 + t) * 8 + (e2 & 7);
                        xg16[slot * 2 + 1] = bf16r(gg);
                    } else if (col < 4160) {
                        dtlow_bf[(size_t)row * 64 + (col - 4096)] = bf16r(v);
                    } else {
                        bc_bf[(size_t)row * 64 + (col - 4160)] = bf16r(v);
                    }
                } else {   // MODE 3
                    v += bias[col];
                    v = (v > 20.f) ? v : __logf(1.f + __expf(v));
                    int bb = row >> 11, t = row & 2047;
                    dtp[((size_t)(bb * 256 + (col >> 3)) * 2048 + t) * 8 + (col & 7)] = v;
                }
            }
        }
    }
}

// ------------------------------------------------- GEMM4: 128x64 tiles, packed A
// out = resid + y_packed @ Wout^T.  A is packed bf16 [b][eg][t][8] (e = K dim).
__global__ __launch_bounds__(256) void gemm4_n64(
    const ushort* __restrict__ A, const ushort* __restrict__ B,
    float* __restrict__ C, const float* __restrict__ resid)
{
    __shared__ __align__(16) ushort As[128 * 32];
    __shared__ __align__(16) ushort Bs[64 * 32];
    int tid = threadIdx.x;
    int bm = blockIdx.x * 128, bn = blockIdx.y * 64;
    int wave = tid >> 6, lane = tid & 63;
    int wm = (wave & 1) * 64, wn = (wave >> 1) * 32;
    int quad = lane >> 4, m16 = lane & 15;
    int grow = tid >> 2;
    int gcol = (tid & 3) * 8;
    int bb = bm >> 11, t0 = bm & 2047;
    const size_t b0 = (size_t)(bn + grow) * 2048 + gcol;
    char* asw = (char*)As + wave * 1024;
    char* bsw = (char*)Bs + wave * 1024;

    f32x4 acc[4][2] = {};
    for (int k0 = 0; k0 < 2048; k0 += 32) {
        size_t abase = (size_t)(bb * 256 + ((k0 + gcol) >> 3)) * 2048;
        __builtin_amdgcn_global_load_lds((gp_t)(A + (abase + t0 + grow) * 8),      (lp_t)asw,          16, 0, 0);
        __builtin_amdgcn_global_load_lds((gp_t)(A + (abase + t0 + grow + 64) * 8), (lp_t)(asw + 4096), 16, 0, 0);
        __builtin_amdgcn_global_load_lds((gp_t)(B + b0 + k0),                      (lp_t)bsw,          16, 0, 0);
        __syncthreads();
        short8 af[4], bf[2];
        #pragma unroll
        for (int i = 0; i < 4; ++i)
            af[i] = *(const short8*)&As[(wm + i * 16 + m16) * 32 + quad * 8];
        #pragma unroll
        for (int j = 0; j < 2; ++j)
            bf[j] = *(const short8*)&Bs[(wn + j * 16 + m16) * 32 + quad * 8];
        #pragma unroll
        for (int i = 0; i < 4; ++i)
            #pragma unroll
            for (int j = 0; j < 2; ++j)
                acc[i][j] = __builtin_amdgcn_mfma_f32_16x16x32_bf16(
                    af[i], bf[j], acc[i][j], 0, 0, 0);
        __syncthreads();
    }
    #pragma unroll
    for (int i = 0; i < 4; ++i) {
        #pragma unroll
        for (int r = 0; r < 4; ++r) {
            int row = bm + wm + i * 16 + quad * 4 + r;
            #pragma unroll
            for (int j = 0; j < 2; ++j) {
                int col = bn + wn + j * 16 + m16;
                C[(size_t)row * 1024 + col] =
                    acc[i][j][r] + resid[(size_t)row * 1024 + col];
            }
        }
    }
}

// ---------------------------------------------------------------- scan v8
// Packed dense inputs: dtp fp32 / xg bf16x2 in [b][eg][t][8]; bc bf16 [bt][64].
// Chunk-staged (32 t), double-buffered LDS, DPP-partial reduce, y staged in
// swizzled LDS tile and flushed as packed 512 B-contiguous bf16.
__global__ __launch_bounds__(256) void scan_kernel(
    const float* __restrict__ dtp,
    const unsigned* __restrict__ xgp,
    const ushort* __restrict__ bc_bf,
    const float* __restrict__ A_log_real,
    const float* __restrict__ A_imag,
    const float* __restrict__ D_param,
    unsigned* __restrict__ yq)        // packed bf16 y as uints
{
    const int tid  = threadIdx.x;
    const int lane = tid & 63;
    const int s    = tid & 31;
    const int elb  = tid >> 5;                 // 0..7
    const int b    = blockIdx.x >> 8;
    const int eg   = blockIdx.x & 255;
    const int e    = eg * 8 + elb;
    const int stt  = tid >> 3, sk  = tid & 7;  // dxp/xzs staging: t, e
    const int btp  = tid >> 4, bsp = tid & 15; // bc staging: t-pair, s-pair
    const int q    = (lane >> 4) & 1;

    __shared__ __align__(16) float dxp[2][8][17][4];  // [e][tp]{dt0,dtx0,dt1,dtx1}
    __shared__ __align__(16) float xzs[2][8][34][2];  // [e][t]{D*x, g}
    __shared__ __align__(16) float bcs[2][16][33][4]; // [tp][s]{B0,C0,B1,C1}
    __shared__ __align__(16) float pp[8][2][32];      // [e][half][t] partials
    __shared__ __align__(8)  ushort ytile[2][32][8];  // swizzled y chunk

    const float Ar2  = -__expf(A_log_real[e * D_STATE + s]) * 1.44269504f;
    const float Ai2p = A_imag[e * D_STATE + s] * 0.15915494f;
    const float Dps  = D_param[eg * 8 + sk];
    float hr = 0.f, hi = 0.f;
    const size_t dxbase = (size_t)(b * 256 + eg) * 2048;
    const ushort* bcb = bc_bf + (size_t)b * 2048 * 64;

    float r_d; unsigned r_xg, rB0, rC0, rB1, rC1;

#define LOADC(T0) do {                                                          \
    r_d  = dtp[(dxbase + (T0) + stt) * 8 + sk];                                 \
    r_xg = xgp[(dxbase + (T0) + stt) * 8 + sk];                                 \
    rB0 = *(const unsigned*)&bcb[(size_t)((T0) + 2*btp) * 64 + 2*bsp];          \
    rC0 = *(const unsigned*)&bcb[(size_t)((T0) + 2*btp) * 64 + 32 + 2*bsp];     \
    rB1 = *(const unsigned*)&bcb[(size_t)((T0) + 2*btp + 1) * 64 + 2*bsp];      \
    rC1 = *(const unsigned*)&bcb[(size_t)((T0) + 2*btp + 1) * 64 + 32 + 2*bsp]; \
  } while (0)

#define STAGE(NB) do {                                                          \
    float xv = bflo(r_xg), gv = bfhi(r_xg);                                     \
    *(float2*)&dxp[NB][sk][stt >> 1][(stt & 1) * 2] = make_float2(r_d, r_d * xv); \
    *(float2*)&xzs[NB][sk][stt] = make_float2(Dps * xv, gv);                    \
    *(float4*)&bcs[NB][btp][2*bsp][0]   = make_float4(bflo(rB0), bflo(rC0), bflo(rB1), bflo(rC1)); \
    *(float4*)&bcs[NB][btp][2*bsp+1][0] = make_float4(bfhi(rB0), bfhi(rC0), bfhi(rB1), bfhi(rC1)); \
  } while (0)

    LOADC(0);
    STAGE(0);
    for (int c = 0; c < 64; ++c) {
        const int buf = c & 1;
        __syncthreads();
        if (c > 0 && tid < 128) {          // flush previous chunk's y tile
            int t = tid >> 2, qq = tid & 3;
            unsigned v = *(const unsigned*)&ytile[buf ^ 1][t][(qq ^ (t & 3)) << 1];
            yq[(dxbase + (size_t)(c - 1) * 32) * 4 + tid] = v;
        }
        if (c < 63) LOADC((c + 1) * 32);
        #pragma unroll
        for (int tp = 0; tp < 16; ++tp) {
            float4 dd = *(const float4*)&dxp[buf][elb][tp][0];   // broadcast
            float4 bc = *(const float4*)&bcs[buf][tp][s][0];
            float sc = __builtin_amdgcn_exp2f(Ar2 * dd.x);
            float u  = Ai2p * dd.x;
            float sa = __builtin_amdgcn_sinf(u), ca = __builtin_amdgcn_cosf(u);
            float dAr = sc * ca, dAi = sc * sa;
            float hrn = fmaf(dAr, hr, fmaf(-dAi, hi, dd.y * bc.x));
            hi = fmaf(dAr, hi, dAi * hr); hr = hrn;
            float p0 = hr * bc.y;
            sc = __builtin_amdgcn_exp2f(Ar2 * dd.z);
            u  = Ai2p * dd.z;
            sa = __builtin_amdgcn_sinf(u); ca = __builtin_amdgcn_cosf(u);
            dAr = sc * ca; dAi = sc * sa;
            hrn = fmaf(dAr, hr, fmaf(-dAi, hi, dd.w * bc.z));
            hi = fmaf(dAr, hi, dAi * hr); hr = hrn;
            float p1 = hr * bc.w;
            p0 = dpp_red16(p0);
            p1 = dpp_red16(p1);
            if ((lane & 15) == 15)
                *(float2*)&pp[elb][q][2 * tp] = make_float2(p0, p1);
        }
        // gate (wave-private pp, in-order DS pipe)
        {
            float pA = pp[elb][0][s];
            float pB = pp[elb][1][s];
            float2 xg2 = *(const float2*)&xzs[buf][elb][s];
            ytile[buf][s][(((elb >> 1) ^ (s & 3)) << 1) | (elb & 1)] =
                bf16r((pA + pB + xg2.x) * xg2.y);
        }
        if (c < 63) STAGE(buf ^ 1);
    }
    __syncthreads();
    if (tid < 128) {                       // flush chunk 63
        int t = tid >> 2, qq = tid & 3;
        unsigned v = *(const unsigned*)&ytile[1][t][(qq ^ (t & 3)) << 1];
        yq[(dxbase + (size_t)63 * 32) * 4 + tid] = v;
    }
#undef LOADC
#undef STAGE
}

// ---------------------------------------------------------------- launch
extern "C" void kernel_launch(void* const* d_in, const int* in_sizes, int n_in,
                              void* d_out, int out_size, void* d_ws, size_t ws_size,
                              hipStream_t stream) {
    const float* x          = (const float*)d_in[0];
    const float* W_in       = (const float*)d_in[1];
    const float* W_x        = (const float*)d_in[2];
    const float* W_dt       = (const float*)d_in[3];
    const float* b_dt       = (const float*)d_in[4];
    const float* A_log_real = (const float*)d_in[5];
    const float* A_imag     = (const float*)d_in[6];
    const float* D_param    = (const float*)d_in[7];
    const float* W_out      = (const float*)d_in[8];
    const float* ln_g       = (const float*)d_in[9];
    const float* ln_b       = (const float*)d_in[10];
    float* out = (float*)d_out;

    char* ws = (char*)d_ws;
    unsigned* xgp      = (unsigned*)(ws);                       // 32 MiB packed {x,g} bf16x2
    float*    dtp      = (float*)  (ws + ((size_t) 32 << 20));  // 32 MiB packed dt fp32
    ushort*   y_pk     = (ushort*) (ws + ((size_t) 64 << 20));  // 16 MiB packed y bf16
    ushort*   dtlow_bf = (ushort*) (ws + ((size_t) 80 << 20));  // 0.5 MiB [4096,64]
    ushort*   bc_bf    = (ushort*) (ws + ((size_t) 81 << 20));  // 0.5 MiB [4096,64]
    ushort*   xn_bf    = (ushort*) (ws + ((size_t) 82 << 20));  // 8 MiB [4096,1024]
    ushort*   Waug     = (ushort*) (ws + ((size_t) 90 << 20));  // 8.25 MiB [4224,1024]
    ushort*   Wout_bf  = (ushort*) (ws + ((size_t) 99 << 20));  // 4 MiB [1024,2048]
    ushort*   Wdt_bf   = (ushort*) (ws + ((size_t)103 << 20));  // 0.25 MiB [2048,64]
    ushort*   Wx_bf    = (ushort*) (ws + ((size_t)104 << 20));  // 0.5 MiB [128,2048]
    ushort*   WinT_bf  = (ushort*) (ws + ((size_t)105 << 20));  // 4 MiB [1024,2048]

    // weight prep (cvt + transpose fused)
    prep_weights<<<8576, 256, 0, stream>>>(W_in, W_out, W_dt, W_x,
                                           Waug, Wout_bf, Wdt_bf, Wx_bf, WinT_bf);
    // W_comb = W_x @ W_in_x -> bf16 into Waug rows 4096..4223
    gemm_bt_bf16<1><<<dim3(1, 8), 256, 0, stream>>>(
        Wx_bf, WinT_bf, (float*)(Waug + (size_t)4096 * 1024), 1024, 2048,
        nullptr, nullptr, nullptr, nullptr, nullptr, nullptr);
    // LayerNorm -> bf16
    ln_kernel<<<BT, 256, 0, stream>>>(x, ln_g, ln_b, xn_bf);
    // GEMM1(aug, scan-pack): writes xgp (x,g), dtlow_bf, bc_bf
    gemm_bt_bf16<2><<<dim3(BT/128, 33), 256, 0, stream>>>(
        xn_bf, Waug, nullptr, 0, D_MODEL,
        nullptr, nullptr, (ushort*)xgp, dtlow_bf, bc_bf, nullptr);
    // GEMM3 (pack-dt): dt = softplus(dt_low @ W_dt^T + b_dt) -> dtp packed
    gemm_bt_bf16<3><<<dim3(BT/128, D_INNER/128), 256, 0, stream>>>(
        dtlow_bf, Wdt_bf, nullptr, 0, DT_RANK,
        nullptr, b_dt, nullptr, nullptr, nullptr, dtp);
    // scan + fused gating -> packed y
    scan_kernel<<<512, 256, 0, stream>>>(dtp, xgp, bc_bf,
                                         A_log_real, A_imag, D_param,
                                         (unsigned*)y_pk);
    // GEMM4: out = residual + y @ W_out^T   (packed-A, 128x64 tiles)
    gemm4_n64<<<dim3(BT/128, D_MODEL/64), 256, 0, stream>>>(
        y_pk, Wout_bf, out, x);
}

// Round 9
// 487.901 us; speedup vs baseline: 1.1317x; 1.0197x over previous
//
#include <hip/hip_runtime.h>
#include <math.h>

#define D_MODEL 1024
#define D_STATE 32
#define D_INNER 2048
#define DT_RANK 64
#define BT 4096            // B*T = 2*2048
#define LN_EPS 1e-5f

typedef __attribute__((ext_vector_type(8))) short short8;
typedef __attribute__((ext_vector_type(4))) float f32x4;
typedef const __attribute__((address_space(1))) void* gp_t;
typedef __attribute__((address_space(3))) void* lp_t;

__device__ __forceinline__ ushort bf16r(float f) {
    unsigned u = __float_as_uint(f);
    u += 0x7fff + ((u >> 16) & 1);          // round-to-nearest-even
    return (ushort)(u >> 16);
}
__device__ __forceinline__ float bflo(unsigned u) { return __uint_as_float(u << 16); }
__device__ __forceinline__ float bfhi(unsigned u) { return __uint_as_float(u & 0xffff0000u); }

// 16-lane (DPP row) partial sum; row sums land in lanes 15/31/47/63.
__device__ __forceinline__ float dpp_red16(float x) {
    int t;
    t = __builtin_amdgcn_update_dpp(0, __float_as_int(x), 0x111, 0xf, 0xf, true);
    x += __int_as_float(t);
    t = __builtin_amdgcn_update_dpp(0, __float_as_int(x), 0x112, 0xf, 0xf, true);
    x += __int_as_float(t);
    t = __builtin_amdgcn_update_dpp(0, __float_as_int(x), 0x114, 0xf, 0xf, true);
    x += __int_as_float(t);
    t = __builtin_amdgcn_update_dpp(0, __float_as_int(x), 0x118, 0xf, 0xf, true);
    x += __int_as_float(t);
    return x;
}

// ---------------- fused: weight cvts (x/z-interleaved Waug) + W_in^T + LayerNorm
__global__ __launch_bounds__(256) void prep_all(
    const float* __restrict__ W_in, const float* __restrict__ W_out,
    const float* __restrict__ W_dt, const float* __restrict__ W_x,
    ushort* __restrict__ Waug, ushort* __restrict__ Wout_bf,
    ushort* __restrict__ Wdt_bf, ushort* __restrict__ Wx_bf,
    ushort* __restrict__ WinT_bf,
    const float* __restrict__ x, const float* __restrict__ ln_g,
    const float* __restrict__ ln_b, ushort* __restrict__ xn) {
    __shared__ float tile[32][33];
    __shared__ float rs[4], rss[4];
    int bid = blockIdx.x;
    if (bid < 4096) {
        // W_in -> Waug with x/z row interleave: row e -> 2e, row 2048+e -> 2e+1
        int i = bid * 256 + threadIdx.x;          // float4 index
        int row = i >> 8, cf = i & 255;
        int nrow = (row < 2048) ? (2 * row) : (2 * (row - 2048) + 1);
        float4 v = ((const float4*)W_in)[i];
        ushort4 o;
        o.x = bf16r(v.x); o.y = bf16r(v.y); o.z = bf16r(v.z); o.w = bf16r(v.w);
        ((ushort4*)Waug)[nrow * 256 + cf] = o;
    } else if (bid < 6528) {
        const float* src; ushort* dst; int i;
        if (bid < 6144)      { src = W_out; dst = Wout_bf; i = (bid - 4096) * 256 + threadIdx.x; }
        else if (bid < 6400) { src = W_x;   dst = Wx_bf;   i = (bid - 6144) * 256 + threadIdx.x; }
        else                 { src = W_dt;  dst = Wdt_bf;  i = (bid - 6400) * 256 + threadIdx.x; }
        float4 v = ((const float4*)src)[i];
        ushort4 o;
        o.x = bf16r(v.x); o.y = bf16r(v.y); o.z = bf16r(v.z); o.w = bf16r(v.w);
        ((ushort4*)dst)[i] = o;
    } else if (bid < 8576) {
        // transpose W_in [2048,1024] -> WinT [1024,2048] bf16 (x_ssm half)
        int bid2 = bid - 6528;
        int bx = (bid2 & 63) * 32;   // e base
        int by = (bid2 >> 6) * 32;   // d base
        int tx = threadIdx.x & 31, ty = threadIdx.x >> 5;
        #pragma unroll
        for (int i = 0; i < 32; i += 8)
            tile[ty + i][tx] = W_in[(size_t)(bx + ty + i) * 1024 + by + tx];
        __syncthreads();
        #pragma unroll
        for (int i = 0; i < 32; i += 8)
            WinT_bf[(size_t)(by + ty + i) * 2048 + bx + tx] = bf16r(tile[tx][ty + i]);
    } else {
        // LayerNorm row
        int row = bid - 8576;
        const float4* xr = (const float4*)(x + (size_t)row * D_MODEL);
        float4 v = xr[threadIdx.x];
        float s  = v.x + v.y + v.z + v.w;
        float ss = v.x*v.x + v.y*v.y + v.z*v.z + v.w*v.w;
        #pragma unroll
        for (int off = 32; off > 0; off >>= 1) {
            s  += __shfl_down(s,  off, 64);
            ss += __shfl_down(ss, off, 64);
        }
        int wave = threadIdx.x >> 6;
        if ((threadIdx.x & 63) == 0) { rs[wave] = s; rss[wave] = ss; }
        __syncthreads();
        s  = rs[0] + rs[1] + rs[2] + rs[3];
        ss = rss[0] + rss[1] + rss[2] + rss[3];
        float mu  = s * (1.f / D_MODEL);
        float var = ss * (1.f / D_MODEL) - mu * mu;
        float inv = rsqrtf(var + LN_EPS);
        float4 gv = ((const float4*)ln_g)[threadIdx.x];
        float4 bv = ((const float4*)ln_b)[threadIdx.x];
        ushort4 o;
        o.x = bf16r((v.x - mu) * inv * gv.x + bv.x);
        o.y = bf16r((v.y - mu) * inv * gv.y + bv.y);
        o.z = bf16r((v.z - mu) * inv * gv.z + bv.z);
        o.w = bf16r((v.w - mu) * inv * gv.w + bv.w);
        ((ushort4*)(xn + (size_t)row * D_MODEL))[threadIdx.x] = o;
    }
}

// ------------------------------------------------- bf16 MFMA NT GEMM 128x128
// MODE 0: fp32 C. MODE 1: bf16 C. MODE 2 (GEMM1 scan-pack, x/z interleaved
// cols): col<4096 -> pair (x=even, z=odd) -> packed uint{x,g} dword stores by
// even lanes; col<4160 -> dtlow_bf; else bc_bf. MODE 3 (GEMM3): softplus
// (+bias) -> dtp packed fp32 [b][eg][t][8].
template<int MODE>
__global__ __launch_bounds__(256) void gemm_bt_bf16(
    const ushort* __restrict__ A, const ushort* __restrict__ B,
    float* __restrict__ C, int ldc, int K,
    const float* __restrict__ bias,
    unsigned* __restrict__ xgp, ushort* __restrict__ dtlow_bf,
    ushort* __restrict__ bc_bf, float* __restrict__ dtp)
{
    __shared__ __align__(16) ushort As[128 * 32];   // [m][k] dense
    __shared__ __align__(16) ushort Bs[128 * 32];   // [n][k] dense
    int tid = threadIdx.x;
    int bm = blockIdx.x * 128, bn = blockIdx.y * 128;
    int wave = tid >> 6, lane = tid & 63;
    int wm = (wave & 1) * 64, wn = (wave >> 1) * 64;
    int quad = lane >> 4, m16 = lane & 15;
    int grow = tid >> 2;
    int gcol = (tid & 3) * 8;
    const size_t a0 = (size_t)(bm + grow) * K + gcol;
    const size_t b0 = (size_t)(bn + grow) * K + gcol;
    char* asw = (char*)As + wave * 1024;
    char* bsw = (char*)Bs + wave * 1024;

    f32x4 acc[4][4] = {};
    for (int k0 = 0; k0 < K; k0 += 32) {
        __builtin_amdgcn_global_load_lds((gp_t)(A + a0 + k0),                 (lp_t)asw,          16, 0, 0);
        __builtin_amdgcn_global_load_lds((gp_t)(A + a0 + (size_t)64*K + k0),  (lp_t)(asw + 4096), 16, 0, 0);
        __builtin_amdgcn_global_load_lds((gp_t)(B + b0 + k0),                 (lp_t)bsw,          16, 0, 0);
        __builtin_amdgcn_global_load_lds((gp_t)(B + b0 + (size_t)64*K + k0),  (lp_t)(bsw + 4096), 16, 0, 0);
        __syncthreads();
        short8 af[4], bf[4];
        #pragma unroll
        for (int i = 0; i < 4; ++i)
            af[i] = *(const short8*)&As[(wm + i * 16 + m16) * 32 + quad * 8];
        #pragma unroll
        for (int j = 0; j < 4; ++j)
            bf[j] = *(const short8*)&Bs[(wn + j * 16 + m16) * 32 + quad * 8];
        #pragma unroll
        for (int i = 0; i < 4; ++i)
            #pragma unroll
            for (int j = 0; j < 4; ++j)
                acc[i][j] = __builtin_amdgcn_mfma_f32_16x16x32_bf16(
                    af[i], bf[j], acc[i][j], 0, 0, 0);
        __syncthreads();
    }
    #pragma unroll
    for (int i = 0; i < 4; ++i) {
        #pragma unroll
        for (int r = 0; r < 4; ++r) {
            int row = bm + wm + i * 16 + quad * 4 + r;
            #pragma unroll
            for (int j = 0; j < 4; ++j) {
                int col = bn + wn + j * 16 + m16;
                float v = acc[i][j][r];
                if (MODE == 0) {
                    C[(size_t)row * ldc + col] = v;
                } else if (MODE == 1) {
                    ((ushort*)C)[(size_t)row * ldc + col] = bf16r(v);
                } else if (MODE == 2) {
                    int bb = row >> 11, t = row & 2047;
                    if (col < 4096) {
                        // even col = x_e, odd col = z_e (e = col>>1)
                        float gg = v / (1.f + __expf(-v));       // valid on odd lanes
                        float gpart = __shfl_xor(gg, 1);         // even lanes get g
                        if ((m16 & 1) == 0) {
                            int e2 = col >> 1;
                            unsigned pk = (unsigned)bf16r(v) | ((unsigned)bf16r(gpart) << 16);
                            xgp[((size_t)(bb * 256 + (e2 >> 3)) * 2048 + t) * 8 + (e2 & 7)] = pk;
                        }
                    } else if (col < 4160) {
                        dtlow_bf[(size_t)row * 64 + (col - 4096)] = bf16r(v);
                    } else {
                        bc_bf[(size_t)row * 64 + (col - 4160)] = bf16r(v);
                    }
                } else {   // MODE 3
                    v += bias[col];
                    v = (v > 20.f) ? v : __logf(1.f + __expf(v));
                    int bb = row >> 11, t = row & 2047;
                    dtp[((size_t)(bb * 256 + (col >> 3)) * 2048 + t) * 8 + (col & 7)] = v;
                }
            }
        }
    }
}

// ------------------------------------------------- GEMM4: 128x64 tiles, packed A
__global__ __launch_bounds__(256) void gemm4_n64(
    const ushort* __restrict__ A, const ushort* __restrict__ B,
    float* __restrict__ C, const float* __restrict__ resid)
{
    __shared__ __align__(16) ushort As[128 * 32];
    __shared__ __align__(16) ushort Bs[64 * 32];
    int tid = threadIdx.x;
    int bm = blockIdx.x * 128, bn = blockIdx.y * 64;
    int wave = tid >> 6, lane = tid & 63;
    int wm = (wave & 1) * 64, wn = (wave >> 1) * 32;
    int quad = lane >> 4, m16 = lane & 15;
    int grow = tid >> 2;
    int gcol = (tid & 3) * 8;
    int bb = bm >> 11, t0 = bm & 2047;
    const size_t b0 = (size_t)(bn + grow) * 2048 + gcol;
    char* asw = (char*)As + wave * 1024;
    char* bsw = (char*)Bs + wave * 1024;

    f32x4 acc[4][2] = {};
    for (int k0 = 0; k0 < 2048; k0 += 32) {
        size_t abase = (size_t)(bb * 256 + ((k0 + gcol) >> 3)) * 2048;
        __builtin_amdgcn_global_load_lds((gp_t)(A + (abase + t0 + grow) * 8),      (lp_t)asw,          16, 0, 0);
        __builtin_amdgcn_global_load_lds((gp_t)(A + (abase + t0 + grow + 64) * 8), (lp_t)(asw + 4096), 16, 0, 0);
        __builtin_amdgcn_global_load_lds((gp_t)(B + b0 + k0),                      (lp_t)bsw,          16, 0, 0);
        __syncthreads();
        short8 af[4], bf[2];
        #pragma unroll
        for (int i = 0; i < 4; ++i)
            af[i] = *(const short8*)&As[(wm + i * 16 + m16) * 32 + quad * 8];
        #pragma unroll
        for (int j = 0; j < 2; ++j)
            bf[j] = *(const short8*)&Bs[(wn + j * 16 + m16) * 32 + quad * 8];
        #pragma unroll
        for (int i = 0; i < 4; ++i)
            #pragma unroll
            for (int j = 0; j < 2; ++j)
                acc[i][j] = __builtin_amdgcn_mfma_f32_16x16x32_bf16(
                    af[i], bf[j], acc[i][j], 0, 0, 0);
        __syncthreads();
    }
    #pragma unroll
    for (int i = 0; i < 4; ++i) {
        #pragma unroll
        for (int r = 0; r < 4; ++r) {
            int row = bm + wm + i * 16 + quad * 4 + r;
            #pragma unroll
            for (int j = 0; j < 2; ++j) {
                int col = bn + wn + j * 16 + m16;
                C[(size_t)row * 1024 + col] =
                    acc[i][j][r] + resid[(size_t)row * 1024 + col];
            }
        }
    }
}

// ---------------------------------------------------------------- scan v8
__global__ __launch_bounds__(256) void scan_kernel(
    const float* __restrict__ dtp,
    const unsigned* __restrict__ xgp,
    const ushort* __restrict__ bc_bf,
    const float* __restrict__ A_log_real,
    const float* __restrict__ A_imag,
    const float* __restrict__ D_param,
    unsigned* __restrict__ yq)        // packed bf16 y as uints
{
    const int tid  = threadIdx.x;
    const int lane = tid & 63;
    const int s    = tid & 31;
    const int elb  = tid >> 5;                 // 0..7
    const int b    = blockIdx.x >> 8;
    const int eg   = blockIdx.x & 255;
    const int e    = eg * 8 + elb;
    const int stt  = tid >> 3, sk  = tid & 7;  // dxp/xzs staging: t, e
    const int btp  = tid >> 4, bsp = tid & 15; // bc staging: t-pair, s-pair
    const int q    = (lane >> 4) & 1;

    __shared__ __align__(16) float dxp[2][8][17][4];  // [e][tp]{dt0,dtx0,dt1,dtx1}
    __shared__ __align__(16) float xzs[2][8][34][2];  // [e][t]{D*x, g}
    __shared__ __align__(16) float bcs[2][16][33][4]; // [tp][s]{B0,C0,B1,C1}
    __shared__ __align__(16) float pp[8][2][32];      // [e][half][t] partials
    __shared__ __align__(8)  ushort ytile[2][32][8];  // swizzled y chunk

    const float Ar2  = -__expf(A_log_real[e * D_STATE + s]) * 1.44269504f;
    const float Ai2p = A_imag[e * D_STATE + s] * 0.15915494f;
    const float Dps  = D_param[eg * 8 + sk];
    float hr = 0.f, hi = 0.f;
    const size_t dxbase = (size_t)(b * 256 + eg) * 2048;
    const ushort* bcb = bc_bf + (size_t)b * 2048 * 64;

    float r_d; unsigned r_xg, rB0, rC0, rB1, rC1;

#define LOADC(T0) do {                                                          \
    r_d  = dtp[(dxbase + (T0) + stt) * 8 + sk];                                 \
    r_xg = xgp[(dxbase + (T0) + stt) * 8 + sk];                                 \
    rB0 = *(const unsigned*)&bcb[(size_t)((T0) + 2*btp) * 64 + 2*bsp];          \
    rC0 = *(const unsigned*)&bcb[(size_t)((T0) + 2*btp) * 64 + 32 + 2*bsp];     \
    rB1 = *(const unsigned*)&bcb[(size_t)((T0) + 2*btp + 1) * 64 + 2*bsp];      \
    rC1 = *(const unsigned*)&bcb[(size_t)((T0) + 2*btp + 1) * 64 + 32 + 2*bsp]; \
  } while (0)

#define STAGE(NB) do {                                                          \
    float xv = bflo(r_xg), gv = bfhi(r_xg);                                     \
    *(float2*)&dxp[NB][sk][stt >> 1][(stt & 1) * 2] = make_float2(r_d, r_d * xv); \
    *(float2*)&xzs[NB][sk][stt] = make_float2(Dps * xv, gv);                    \
    *(float4*)&bcs[NB][btp][2*bsp][0]   = make_float4(bflo(rB0), bflo(rC0), bflo(rB1), bflo(rC1)); \
    *(float4*)&bcs[NB][btp][2*bsp+1][0] = make_float4(bfhi(rB0), bfhi(rC0), bfhi(rB1), bfhi(rC1)); \
  } while (0)

    LOADC(0);
    STAGE(0);
    for (int c = 0; c < 64; ++c) {
        const int buf = c & 1;
        __syncthreads();
        if (c > 0 && tid < 128) {          // flush previous chunk's y tile
            int t = tid >> 2, qq = tid & 3;
            unsigned v = *(const unsigned*)&ytile[buf ^ 1][t][(qq ^ (t & 3)) << 1];
            yq[(dxbase + (size_t)(c - 1) * 32) * 4 + tid] = v;
        }
        if (c < 63) LOADC((c + 1) * 32);
        #pragma unroll
        for (int tp = 0; tp < 16; ++tp) {
            float4 dd = *(const float4*)&dxp[buf][elb][tp][0];   // broadcast
            float4 bc = *(const float4*)&bcs[buf][tp][s][0];
            float sc = __builtin_amdgcn_exp2f(Ar2 * dd.x);
            float u  = Ai2p * dd.x;
            float sa = __builtin_amdgcn_sinf(u), ca = __builtin_amdgcn_cosf(u);
            float dAr = sc * ca, dAi = sc * sa;
            float hrn = fmaf(dAr, hr, fmaf(-dAi, hi, dd.y * bc.x));
            hi = fmaf(dAr, hi, dAi * hr); hr = hrn;
            float p0 = hr * bc.y;
            sc = __builtin_amdgcn_exp2f(Ar2 * dd.z);
            u  = Ai2p * dd.z;
            sa = __builtin_amdgcn_sinf(u); ca = __builtin_amdgcn_cosf(u);
            dAr = sc * ca; dAi = sc * sa;
            hrn = fmaf(dAr, hr, fmaf(-dAi, hi, dd.w * bc.z));
            hi = fmaf(dAr, hi, dAi * hr); hr = hrn;
            float p1 = hr * bc.w;
            p0 = dpp_red16(p0);
            p1 = dpp_red16(p1);
            if ((lane & 15) == 15)
                *(float2*)&pp[elb][q][2 * tp] = make_float2(p0, p1);
        }
        {
            float pA = pp[elb][0][s];
            float pB = pp[elb][1][s];
            float2 xg2 = *(const float2*)&xzs[buf][elb][s];
            ytile[buf][s][(((elb >> 1) ^ (s & 3)) << 1) | (elb & 1)] =
                bf16r((pA + pB + xg2.x) * xg2.y);
        }
        if (c < 63) STAGE(buf ^ 1);
    }
    __syncthreads();
    if (tid < 128) {                       // flush chunk 63
        int t = tid >> 2, qq = tid & 3;
        unsigned v = *(const unsigned*)&ytile[1][t][(qq ^ (t & 3)) << 1];
        yq[(dxbase + (size_t)63 * 32) * 4 + tid] = v;
    }
#undef LOADC
#undef STAGE
}

// ---------------------------------------------------------------- launch
extern "C" void kernel_launch(void* const* d_in, const int* in_sizes, int n_in,
                              void* d_out, int out_size, void* d_ws, size_t ws_size,
                              hipStream_t stream) {
    const float* x          = (const float*)d_in[0];
    const float* W_in       = (const float*)d_in[1];
    const float* W_x        = (const float*)d_in[2];
    const float* W_dt       = (const float*)d_in[3];
    const float* b_dt       = (const float*)d_in[4];
    const float* A_log_real = (const float*)d_in[5];
    const float* A_imag     = (const float*)d_in[6];
    const float* D_param    = (const float*)d_in[7];
    const float* W_out      = (const float*)d_in[8];
    const float* ln_g       = (const float*)d_in[9];
    const float* ln_b       = (const float*)d_in[10];
    float* out = (float*)d_out;

    char* ws = (char*)d_ws;
    unsigned* xgp      = (unsigned*)(ws);                       // 32 MiB packed {x,g}
    float*    dtp      = (float*)  (ws + ((size_t) 32 << 20));  // 32 MiB packed dt fp32
    ushort*   y_pk     = (ushort*) (ws + ((size_t) 64 << 20));  // 16 MiB packed y bf16
    ushort*   dtlow_bf = (ushort*) (ws + ((size_t) 80 << 20));  // 0.5 MiB [4096,64]
    ushort*   bc_bf    = (ushort*) (ws + ((size_t) 81 << 20));  // 0.5 MiB [4096,64]
    ushort*   xn_bf    = (ushort*) (ws + ((size_t) 82 << 20));  // 8 MiB [4096,1024]
    ushort*   Waug     = (ushort*) (ws + ((size_t) 90 << 20));  // 8.25 MiB [4224,1024]
    ushort*   Wout_bf  = (ushort*) (ws + ((size_t) 99 << 20));  // 4 MiB [1024,2048]
    ushort*   Wdt_bf   = (ushort*) (ws + ((size_t)103 << 20));  // 0.25 MiB [2048,64]
    ushort*   Wx_bf    = (ushort*) (ws + ((size_t)104 << 20));  // 0.5 MiB [128,2048]
    ushort*   WinT_bf  = (ushort*) (ws + ((size_t)105 << 20));  // 4 MiB [1024,2048]

    // prep: weight cvts (interleaved Waug) + W_in transpose + LayerNorm
    prep_all<<<12672, 256, 0, stream>>>(W_in, W_out, W_dt, W_x,
                                        Waug, Wout_bf, Wdt_bf, Wx_bf, WinT_bf,
                                        x, ln_g, ln_b, xn_bf);
    // W_comb = W_x @ W_in_x -> bf16 into Waug rows 4096..4223
    gemm_bt_bf16<1><<<dim3(1, 8), 256, 0, stream>>>(
        Wx_bf, WinT_bf, (float*)(Waug + (size_t)4096 * 1024), 1024, 2048,
        nullptr, nullptr, nullptr, nullptr, nullptr);
    // GEMM1(aug, scan-pack): writes xgp (x,g packed dwords), dtlow_bf, bc_bf
    gemm_bt_bf16<2><<<dim3(BT/128, 33), 256, 0, stream>>>(
        xn_bf, Waug, nullptr, 0, D_MODEL,
        nullptr, xgp, dtlow_bf, bc_bf, nullptr);
    // GEMM3 (pack-dt): dt = softplus(dt_low @ W_dt^T + b_dt) -> dtp packed
    gemm_bt_bf16<3><<<dim3(BT/128, D_INNER/128), 256, 0, stream>>>(
        dtlow_bf, Wdt_bf, nullptr, 0, DT_RANK,
        b_dt, nullptr, nullptr, nullptr, dtp);
    // scan + fused gating -> packed y
    scan_kernel<<<512, 256, 0, stream>>>(dtp, xgp, bc_bf,
                                         A_log_real, A_imag, D_param,
                                         (unsigned*)y_pk);
    // GEMM4: out = residual + y @ W_out^T   (packed-A, 128x64 tiles)
    gemm4_n64<<<dim3(BT/128, D_MODEL/64), 256, 0, stream>>>(
        y_pk, Wout_bf, out, x);
}